// Round 1
// baseline (1168.901 us; speedup 1.0000x reference)
//
#include <hip/hip_runtime.h>
#include <math.h>

#define N_NODES 10000
#define N_EDGES 320000

#define SQRT3F     1.7320508075688772f
#define INV_SQRT3F 0.5773502691896258f
#define INV_SQRT2F 0.7071067811865476f

// ---------------------------------------------------------------------------
// Kernel 1: per-node linear transforms.
// Outputs (workspace, fp32):
//   s_t[n][64]       = nf_s @ W_nl0
//   v_t[n][96]       (layout k*3+i) = einsum('mi,mk->ki', v, W_nl1)
//   skip_s[n][96]    = nf_s @ W_skip0
//   skip_v[n][96]    (layout k*3+i) = einsum('mi,mk->ki', v, W_skip1)
// One thread per output element (352 per node).
// ---------------------------------------------------------------------------
__global__ __launch_bounds__(256) void node_prep(
    const float* __restrict__ nf,
    const float* __restrict__ Wskip0,
    const float* __restrict__ Wskip1,
    const float* __restrict__ Wnl0,
    const float* __restrict__ Wnl1,
    float* __restrict__ s_t,
    float* __restrict__ v_t,
    float* __restrict__ skip_s,
    float* __restrict__ skip_v)
{
    int gid = blockIdx.x * blockDim.x + threadIdx.x;
    if (gid >= N_NODES * 352) return;
    int n = gid / 352;
    int j = gid - n * 352;
    const float* nfn = nf + (size_t)n * 160;

    if (j < 64) {
        float acc = 0.f;
        #pragma unroll 8
        for (int k = 0; k < 64; ++k) acc += nfn[k] * Wnl0[k * 64 + j];
        s_t[(size_t)n * 64 + j] = acc;
    } else if (j < 160) {
        int c = j - 64;
        float acc = 0.f;
        #pragma unroll 8
        for (int k = 0; k < 64; ++k) acc += nfn[k] * Wskip0[k * 96 + c];
        skip_s[(size_t)n * 96 + c] = acc;
    } else if (j < 256) {
        int t = j - 160;
        int k = t / 3, i = t - 3 * k;
        float acc = 0.f;
        #pragma unroll 8
        for (int m = 0; m < 32; ++m) acc += nfn[64 + m * 3 + i] * Wnl1[m * 32 + k];
        v_t[(size_t)n * 96 + t] = acc;
    } else {
        int t = j - 256;
        int k = t / 3, i = t - 3 * k;
        float acc = 0.f;
        #pragma unroll 8
        for (int m = 0; m < 32; ++m) acc += nfn[64 + m * 3 + i] * Wskip1[m * 32 + k];
        skip_v[(size_t)n * 96 + t] = acc;
    }
}

// ---------------------------------------------------------------------------
// Kernel 2: fused edge MLP + tensor-product message + scatter-add.
// 256 threads, 32 edges per workgroup.
//   phase 0: stage ef tile + sh1 + src/dst
//   phase 1: hidden = relu(ef @ W_fc1)      (LDS)
//   phase 2: w = hidden @ W_fc2             (LDS, 32x224)
//   phase 3: 8 threads/edge compute 480 message elems, atomicAdd into agg[src]
// ---------------------------------------------------------------------------
__global__ __launch_bounds__(256) void edge_kernel(
    const float* __restrict__ edge_attr,
    const float* __restrict__ edge_feature,
    const float* __restrict__ Wfc1,
    const float* __restrict__ Wfc2,
    const int* __restrict__ edge_index,
    const float* __restrict__ s_t,
    const float* __restrict__ v_t,
    float* __restrict__ agg)
{
    __shared__ float ef_s[32][64];    // 8 KB
    __shared__ float hid_s[32][64];   // 8 KB
    __shared__ float w_s[32][224];    // 28 KB
    __shared__ float sh_s[32][3];
    __shared__ int   src_s[32];
    __shared__ int   dst_s[32];

    const int tid = threadIdx.x;
    const int e0  = blockIdx.x * 32;

    // ---- phase 0: load edge features + attrs ----
    #pragma unroll
    for (int r = 0; r < 8; ++r) {
        int idx = tid + r * 256;
        ef_s[idx >> 6][idx & 63] = edge_feature[(size_t)e0 * 64 + idx];
    }
    if (tid < 32) {
        int e = e0 + tid;
        float x = edge_attr[(size_t)e * 3 + 0];
        float y = edge_attr[(size_t)e * 3 + 1];
        float z = edge_attr[(size_t)e * 3 + 2];
        float inv = SQRT3F / sqrtf(x * x + y * y + z * z);
        sh_s[tid][0] = x * inv;
        sh_s[tid][1] = y * inv;
        sh_s[tid][2] = z * inv;
        src_s[tid] = edge_index[e];
        dst_s[tid] = edge_index[N_EDGES + e];
    }
    __syncthreads();

    // ---- phase 1: hidden = relu(ef @ Wfc1) ----
    {
        int h  = tid & 63;
        int eb = tid >> 6;  // 0..3
        float acc[8];
        #pragma unroll
        for (int je = 0; je < 8; ++je) acc[je] = 0.f;
        for (int k = 0; k < 64; ++k) {
            float w1 = Wfc1[k * 64 + h];
            #pragma unroll
            for (int je = 0; je < 8; ++je)
                acc[je] += ef_s[eb * 8 + je][k] * w1;
        }
        #pragma unroll
        for (int je = 0; je < 8; ++je)
            hid_s[eb * 8 + je][h] = fmaxf(acc[je], 0.f);
    }
    __syncthreads();

    // ---- phase 2: w = hidden @ Wfc2 ----
    {
        int c7 = tid & 31;  // c = c7 + 32*j, j=0..6
        int e4 = tid >> 5;  // e = e4 + 8*m, m=0..3
        float acc[4][7];
        #pragma unroll
        for (int m = 0; m < 4; ++m)
            #pragma unroll
            for (int j = 0; j < 7; ++j) acc[m][j] = 0.f;
        for (int k = 0; k < 64; ++k) {
            float wv[7];
            #pragma unroll
            for (int j = 0; j < 7; ++j) wv[j] = Wfc2[k * 224 + c7 + 32 * j];
            float hv[4];
            #pragma unroll
            for (int m = 0; m < 4; ++m) hv[m] = hid_s[e4 + 8 * m][k];
            #pragma unroll
            for (int m = 0; m < 4; ++m)
                #pragma unroll
                for (int j = 0; j < 7; ++j) acc[m][j] += hv[m] * wv[j];
        }
        #pragma unroll
        for (int m = 0; m < 4; ++m)
            #pragma unroll
            for (int j = 0; j < 7; ++j)
                w_s[e4 + 8 * m][c7 + 32 * j] = acc[m][j];
    }
    __syncthreads();

    // ---- phase 3: messages + scatter ----
    {
        int et = tid >> 3;  // 0..31
        int j  = tid & 7;
        int src = src_s[et];
        int dst = dst_s[et];
        float shx = sh_s[et][0], shy = sh_s[et][1], shz = sh_s[et][2];
        const float* xs = s_t + (size_t)dst * 64;
        const float* xv = v_t + (size_t)dst * 96;
        float* aggp = agg + (size_t)src * 480;
        const float* we = w_s[et];

        for (int idx = j; idx < 480; idx += 8) {
            float val;
            if (idx < 64) {
                val = we[idx] * xs[idx];
            } else if (idx < 96) {
                int k = idx - 64;
                float a0 = xv[3 * k], a1 = xv[3 * k + 1], a2 = xv[3 * k + 2];
                val = we[160 + k] * (a0 * shx + a1 * shy + a2 * shz) * INV_SQRT3F;
            } else if (idx < 288) {
                int t = idx - 96;
                int k = t / 3, i = t - 3 * k;
                float sh = (i == 0) ? shx : ((i == 1) ? shy : shz);
                val = we[64 + k] * xs[k] * sh;
            } else if (idx < 384) {
                int t = idx - 288;
                int k = t / 3, i = t - 3 * k;
                val = we[128 + k] * xv[3 * k + i];
            } else {
                int t = idx - 384;
                int k = t / 3, i = t - 3 * k;
                float a0 = xv[3 * k], a1 = xv[3 * k + 1], a2 = xv[3 * k + 2];
                float c;
                if (i == 0)      c = a1 * shz - a2 * shy;
                else if (i == 1) c = a2 * shx - a0 * shz;
                else             c = a0 * shy - a1 * shx;
                val = we[192 + k] * c * INV_SQRT2F;
            }
            atomicAdd(aggp + idx, val);
        }
    }
}

// ---------------------------------------------------------------------------
// Kernel 3: per-node output transform + gating. One block (128 thr) per node.
// ---------------------------------------------------------------------------
__global__ __launch_bounds__(128) void out_kernel(
    const float* __restrict__ agg,
    const float* __restrict__ Wout_s,
    const float* __restrict__ Wout_v,
    const float* __restrict__ skip_s,
    const float* __restrict__ skip_v,
    float* __restrict__ out)
{
    __shared__ float aggl[480];
    __shared__ float os_s[96];
    const int n = blockIdx.x;
    const int tid = threadIdx.x;

    for (int idx = tid; idx < 480; idx += 128)
        aggl[idx] = agg[(size_t)n * 480 + idx] * (1.f / 32.f);
    __syncthreads();

    if (tid < 96) {
        float acc = skip_s[(size_t)n * 96 + tid];
        for (int r = 0; r < 96; ++r) acc += aggl[r] * Wout_s[r * 96 + tid];
        os_s[tid] = acc;
    }
    __syncthreads();

    if (tid < 64) {
        float x = os_s[tid];
        out[(size_t)n * 160 + tid] = x / (1.f + expf(-x));  // silu
    }
    if (tid < 96) {
        int t = tid;
        int k = t / 3, i = t - 3 * k;
        float acc = skip_v[(size_t)n * 96 + t];
        #pragma unroll 8
        for (int m = 0; m < 128; ++m)
            acc += aggl[96 + m * 3 + i] * Wout_v[m * 32 + k];
        float g = os_s[64 + k];
        g = 1.f / (1.f + expf(-g));  // sigmoid gate
        out[(size_t)n * 160 + 64 + t] = g * acc;
    }
}

// ---------------------------------------------------------------------------
extern "C" void kernel_launch(void* const* d_in, const int* in_sizes, int n_in,
                              void* d_out, int out_size, void* d_ws, size_t ws_size,
                              hipStream_t stream)
{
    const float* nf     = (const float*)d_in[0];
    const float* ea     = (const float*)d_in[1];
    const float* ef     = (const float*)d_in[2];
    const float* Wskip0 = (const float*)d_in[3];
    const float* Wskip1 = (const float*)d_in[4];
    const float* Wnl0   = (const float*)d_in[5];
    const float* Wnl1   = (const float*)d_in[6];
    const float* Wfc1   = (const float*)d_in[7];
    const float* Wfc2   = (const float*)d_in[8];
    const float* Wout_s = (const float*)d_in[9];
    const float* Wout_v = (const float*)d_in[10];
    const int*   eidx   = (const int*)d_in[11];
    float* out = (float*)d_out;
    float* ws  = (float*)d_ws;

    // workspace layout (fp32 elements)
    float* s_t    = ws;                 // 10000*64
    float* v_t    = ws + 640000;        // 10000*96
    float* skip_s = ws + 1600000;       // 10000*96
    float* skip_v = ws + 2560000;       // 10000*96
    float* agg    = ws + 3520000;       // 10000*480

    hipMemsetAsync(agg, 0, (size_t)N_NODES * 480 * sizeof(float), stream);

    node_prep<<<(N_NODES * 352 + 255) / 256, 256, 0, stream>>>(
        nf, Wskip0, Wskip1, Wnl0, Wnl1, s_t, v_t, skip_s, skip_v);

    edge_kernel<<<N_EDGES / 32, 256, 0, stream>>>(
        ea, ef, Wfc1, Wfc2, eidx, s_t, v_t, agg);

    out_kernel<<<N_NODES, 128, 0, stream>>>(
        agg, Wout_s, Wout_v, skip_s, skip_v, out);
}

// Round 2
// 542.698 us; speedup vs baseline: 2.1539x; 2.1539x over previous
//
#include <hip/hip_runtime.h>
#include <math.h>

#define N_NODES 10000
#define N_EDGES 320000

#define SQRT3F     1.7320508075688772f
#define INV_SQRT3F 0.5773502691896258f
#define INV_SQRT2F 0.7071067811865476f

// ---------------------------------------------------------------------------
// Kernel 1: per-node linear transforms into combined st_vt[n][160]:
//   [0..63]   s_t  = nf_s @ W_nl0
//   [64..159] v_t  (layout k*3+i) = einsum('mi,mk->ki', v, W_nl1)
// ---------------------------------------------------------------------------
__global__ __launch_bounds__(256) void node_prep(
    const float* __restrict__ nf,
    const float* __restrict__ Wnl0,
    const float* __restrict__ Wnl1,
    float* __restrict__ st_vt)
{
    int gid = blockIdx.x * blockDim.x + threadIdx.x;
    if (gid >= N_NODES * 160) return;
    int n = gid / 160;
    int j = gid - n * 160;
    const float* nfn = nf + (size_t)n * 160;

    float acc = 0.f;
    if (j < 64) {
        #pragma unroll 8
        for (int k = 0; k < 64; ++k) acc += nfn[k] * Wnl0[k * 64 + j];
    } else {
        int t = j - 64;
        int k = t / 3, i = t - 3 * k;
        #pragma unroll 8
        for (int m = 0; m < 32; ++m) acc += nfn[64 + m * 3 + i] * Wnl1[m * 32 + k];
    }
    st_vt[(size_t)n * 160 + j] = acc;
}

// ---------------------------------------------------------------------------
// Sorting: histogram of src, exclusive scan, scatter to order[].
// ---------------------------------------------------------------------------
__global__ __launch_bounds__(256) void hist_kernel(
    const int* __restrict__ eidx, int* __restrict__ cnt)
{
    int e = blockIdx.x * 256 + threadIdx.x;
    if (e < N_EDGES) atomicAdd(&cnt[eidx[e]], 1);
}

__global__ __launch_bounds__(1024) void scan_kernel(
    const int* __restrict__ cnt, int* __restrict__ row_start)
{
    __shared__ int part[1024];
    const int t = threadIdx.x;
    const int CH = 10;  // 1024*10 >= 10000
    int base = t * CH;
    int s = 0;
    for (int i = 0; i < CH; ++i) {
        int idx = base + i;
        if (idx < N_NODES) s += cnt[idx];
    }
    part[t] = s;
    __syncthreads();
    for (int off = 1; off < 1024; off <<= 1) {
        int v = (t >= off) ? part[t - off] : 0;
        __syncthreads();
        part[t] += v;
        __syncthreads();
    }
    int run = (t == 0) ? 0 : part[t - 1];
    for (int i = 0; i < CH; ++i) {
        int idx = base + i;
        if (idx < N_NODES) { row_start[idx] = run; run += cnt[idx]; }
    }
    if (t == 1023) row_start[N_NODES] = run;
}

__global__ __launch_bounds__(256) void scatter_kernel(
    const int* __restrict__ eidx, const int* __restrict__ row_start,
    int* __restrict__ fill, int* __restrict__ order)
{
    int e = blockIdx.x * 256 + threadIdx.x;
    if (e >= N_EDGES) return;
    int s = eidx[e];
    int p = atomicAdd(&fill[s], 1);
    order[row_start[s] + p] = e;
}

// ---------------------------------------------------------------------------
// Kernel 2: fused edge MLP + tensor-product message + segmented scatter.
// 256 threads, 32 SORTED edges per workgroup (src non-decreasing in block).
// LDS: w_s (28K) + uni (20K: ef/hid phases 0-2, then dst features) ~= 50 KB.
// Phase 3: thread owns output components {tid, tid+256}; register-accumulates
// per src-segment, flushing with one global atomicAdd per segment.
// ---------------------------------------------------------------------------
__global__ __launch_bounds__(256) void edge_conv(
    const float* __restrict__ edge_attr,
    const float* __restrict__ edge_feature,
    const float* __restrict__ Wfc1,
    const float* __restrict__ Wfc2,
    const int* __restrict__ edge_index,
    const int* __restrict__ order,
    const float* __restrict__ st_vt,
    float* __restrict__ agg)
{
    __shared__ float w_s[32][224];   // 28 KB
    __shared__ float uni[32 * 160];  // 20 KB: ef_s=uni[0:2048], hid_s=uni[2048:4096]; later df_s=uni[0:5120]
    __shared__ float sh_s[32][3];
    __shared__ int   eid_s[32];
    __shared__ int   src_s[32];
    __shared__ int   dst_s[32];

    const int tid = threadIdx.x;
    float* ef_s  = uni;
    float* hid_s = uni + 2048;
    float* df_s  = uni;

    // ---- phase 0a: edge ids, src/dst, sh1 ----
    if (tid < 32) {
        int e = order[blockIdx.x * 32 + tid];
        eid_s[tid] = e;
        src_s[tid] = edge_index[e];
        dst_s[tid] = edge_index[N_EDGES + e];
        float x = edge_attr[(size_t)e * 3 + 0];
        float y = edge_attr[(size_t)e * 3 + 1];
        float z = edge_attr[(size_t)e * 3 + 2];
        float inv = SQRT3F / sqrtf(x * x + y * y + z * z);
        sh_s[tid][0] = x * inv;
        sh_s[tid][1] = y * inv;
        sh_s[tid][2] = z * inv;
    }
    __syncthreads();

    // ---- phase 0b: gather edge features (rows are 256B contiguous) ----
    #pragma unroll
    for (int r = 0; r < 8; ++r) {
        int idx = tid + r * 256;
        ef_s[idx] = edge_feature[(size_t)eid_s[idx >> 6] * 64 + (idx & 63)];
    }
    __syncthreads();

    // ---- phase 1: hidden = relu(ef @ Wfc1) ----
    {
        int h  = tid & 63;
        int eb = tid >> 6;  // 0..3
        float acc[8];
        #pragma unroll
        for (int je = 0; je < 8; ++je) acc[je] = 0.f;
        for (int k = 0; k < 64; ++k) {
            float w1 = Wfc1[k * 64 + h];
            #pragma unroll
            for (int je = 0; je < 8; ++je)
                acc[je] += ef_s[(eb * 8 + je) * 64 + k] * w1;
        }
        #pragma unroll
        for (int je = 0; je < 8; ++je)
            hid_s[(eb * 8 + je) * 64 + h] = fmaxf(acc[je], 0.f);
    }
    __syncthreads();

    // ---- phase 2: w = hidden @ Wfc2 ----
    {
        int c7 = tid & 31;  // c = c7 + 32*j, j=0..6
        int e4 = tid >> 5;  // e = e4 + 8*m, m=0..3
        float acc[4][7];
        #pragma unroll
        for (int m = 0; m < 4; ++m)
            #pragma unroll
            for (int j = 0; j < 7; ++j) acc[m][j] = 0.f;
        for (int k = 0; k < 64; ++k) {
            float wv[7];
            #pragma unroll
            for (int j = 0; j < 7; ++j) wv[j] = Wfc2[k * 224 + c7 + 32 * j];
            float hv[4];
            #pragma unroll
            for (int m = 0; m < 4; ++m) hv[m] = hid_s[(e4 + 8 * m) * 64 + k];
            #pragma unroll
            for (int m = 0; m < 4; ++m)
                #pragma unroll
                for (int j = 0; j < 7; ++j) acc[m][j] += hv[m] * wv[j];
        }
        #pragma unroll
        for (int m = 0; m < 4; ++m)
            #pragma unroll
            for (int j = 0; j < 7; ++j)
                w_s[e4 + 8 * m][c7 + 32 * j] = acc[m][j];
    }
    __syncthreads();   // hid_s dead from here

    // ---- phase 2.5: gather dst node features into df_s (clobbers uni) ----
    #pragma unroll
    for (int r = 0; r < 20; ++r) {
        int idx = tid + r * 256;
        int e = idx / 160, f = idx - e * 160;
        df_s[idx] = st_vt[(size_t)dst_s[e] * 160 + f];
    }
    __syncthreads();

    // ---- phase 3: messages, register-accumulated per src segment ----
    {
        const int idx0 = tid;
        const int idx1 = 256 + tid;          // valid iff tid < 224
        const bool has1 = (tid < 224);

        auto msg = [&](int idx, int e) -> float {
            const float* we = w_s[e];
            const float* df = df_s + e * 160;
            float shx = sh_s[e][0], shy = sh_s[e][1], shz = sh_s[e][2];
            if (idx < 64) {
                return we[idx] * df[idx];
            } else if (idx < 96) {
                int k = idx - 64;
                return we[160 + k] * (df[64 + 3 * k] * shx + df[65 + 3 * k] * shy +
                                      df[66 + 3 * k] * shz) * INV_SQRT3F;
            } else if (idx < 288) {
                int t = idx - 96;
                int c = t / 3, i = t - 3 * c;
                float sh = (i == 0) ? shx : ((i == 1) ? shy : shz);
                return we[64 + c] * df[c] * sh;
            } else if (idx < 384) {
                int t = idx - 288;
                int k = t / 3, i = t - 3 * k;
                return we[128 + k] * df[64 + 3 * k + i];
            } else {
                int t = idx - 384;
                int k = t / 3, i = t - 3 * k;
                float a0 = df[64 + 3 * k], a1 = df[65 + 3 * k], a2 = df[66 + 3 * k];
                float c;
                if (i == 0)      c = a1 * shz - a2 * shy;
                else if (i == 1) c = a2 * shx - a0 * shz;
                else             c = a0 * shy - a1 * shx;
                return we[192 + k] * c * INV_SQRT2F;
            }
        };

        float a0 = 0.f, a1 = 0.f;
        int cur = src_s[0];
        for (int e = 0; e < 32; ++e) {
            int s = src_s[e];
            if (s != cur) {
                atomicAdd(&agg[(size_t)cur * 480 + idx0], a0);
                if (has1) atomicAdd(&agg[(size_t)cur * 480 + idx1], a1);
                a0 = 0.f; a1 = 0.f; cur = s;
            }
            a0 += msg(idx0, e);
            if (has1) a1 += msg(idx1, e);
        }
        atomicAdd(&agg[(size_t)cur * 480 + idx0], a0);
        if (has1) atomicAdd(&agg[(size_t)cur * 480 + idx1], a1);
    }
}

// ---------------------------------------------------------------------------
// Kernel 3: per-node output transform + gating, skips folded in.
// ---------------------------------------------------------------------------
__global__ __launch_bounds__(128) void out_kernel(
    const float* __restrict__ agg,
    const float* __restrict__ nf,
    const float* __restrict__ Wskip0,
    const float* __restrict__ Wskip1,
    const float* __restrict__ Wout_s,
    const float* __restrict__ Wout_v,
    float* __restrict__ out)
{
    __shared__ float aggl[480];
    __shared__ float os_s[96];
    const int n = blockIdx.x;
    const int tid = threadIdx.x;
    const float* nfn = nf + (size_t)n * 160;

    for (int idx = tid; idx < 480; idx += 128)
        aggl[idx] = agg[(size_t)n * 480 + idx] * (1.f / 32.f);
    __syncthreads();

    if (tid < 96) {
        float acc = 0.f;
        #pragma unroll 8
        for (int k = 0; k < 64; ++k) acc += nfn[k] * Wskip0[k * 96 + tid];
        for (int r = 0; r < 96; ++r) acc += aggl[r] * Wout_s[r * 96 + tid];
        os_s[tid] = acc;
    }
    __syncthreads();

    if (tid < 64) {
        float x = os_s[tid];
        out[(size_t)n * 160 + tid] = x / (1.f + expf(-x));  // silu
    }
    if (tid < 96) {
        int t = tid;
        int k = t / 3, i = t - 3 * k;
        float acc = 0.f;
        #pragma unroll 8
        for (int m = 0; m < 32; ++m) acc += nfn[64 + m * 3 + i] * Wskip1[m * 32 + k];
        #pragma unroll 8
        for (int m = 0; m < 128; ++m) acc += aggl[96 + m * 3 + i] * Wout_v[m * 32 + k];
        float g = os_s[64 + k];
        g = 1.f / (1.f + expf(-g));  // sigmoid gate
        out[(size_t)n * 160 + 64 + t] = g * acc;
    }
}

// ---------------------------------------------------------------------------
extern "C" void kernel_launch(void* const* d_in, const int* in_sizes, int n_in,
                              void* d_out, int out_size, void* d_ws, size_t ws_size,
                              hipStream_t stream)
{
    const float* nf     = (const float*)d_in[0];
    const float* ea     = (const float*)d_in[1];
    const float* ef     = (const float*)d_in[2];
    const float* Wskip0 = (const float*)d_in[3];
    const float* Wskip1 = (const float*)d_in[4];
    const float* Wnl0   = (const float*)d_in[5];
    const float* Wnl1   = (const float*)d_in[6];
    const float* Wfc1   = (const float*)d_in[7];
    const float* Wfc2   = (const float*)d_in[8];
    const float* Wout_s = (const float*)d_in[9];
    const float* Wout_v = (const float*)d_in[10];
    const int*   eidx   = (const int*)d_in[11];
    float* out = (float*)d_out;

    // workspace layout
    int*   cnt       = (int*)d_ws;                       // 10000
    int*   fill      = cnt + 10000;                      // 10000
    int*   row_start = fill + 10000;                     // 10001
    int*   order     = row_start + 10001;                // 320000
    float* st_vt     = (float*)(order + 320003);         // 1,600,000 (aligned)
    float* agg       = st_vt + 1600000;                  // 4,800,000
    // total ~= 27.1 MB

    hipMemsetAsync(cnt, 0, 20000 * sizeof(int), stream);               // cnt+fill
    hipMemsetAsync(agg, 0, (size_t)N_NODES * 480 * sizeof(float), stream);

    node_prep<<<(N_NODES * 160 + 255) / 256, 256, 0, stream>>>(
        nf, Wnl0, Wnl1, st_vt);

    hist_kernel<<<(N_EDGES + 255) / 256, 256, 0, stream>>>(eidx, cnt);
    scan_kernel<<<1, 1024, 0, stream>>>(cnt, row_start);
    scatter_kernel<<<(N_EDGES + 255) / 256, 256, 0, stream>>>(
        eidx, row_start, fill, order);

    edge_conv<<<N_EDGES / 32, 256, 0, stream>>>(
        ea, ef, Wfc1, Wfc2, eidx, order, st_vt, agg);

    out_kernel<<<N_NODES, 128, 0, stream>>>(
        agg, nf, Wskip0, Wskip1, Wout_s, Wout_v, out);
}

// Round 3
// 398.629 us; speedup vs baseline: 2.9323x; 1.3614x over previous
//
#include <hip/hip_runtime.h>
#include <math.h>

#define N_NODES 10000
#define N_EDGES 320000

#define SQRT3F     1.7320508075688772f
#define INV_SQRT3F 0.5773502691896258f
#define INV_SQRT2F 0.7071067811865476f

typedef short bf16x8 __attribute__((ext_vector_type(8)));
typedef float f32x4  __attribute__((ext_vector_type(4)));

static __device__ __forceinline__ unsigned short f2b(float f) {
    unsigned int u = __float_as_uint(f);
    unsigned int r = (u + 0x7fffu + ((u >> 16) & 1u)) >> 16;   // RNE
    return (unsigned short)r;
}
static __device__ __forceinline__ float b2f(unsigned short h) {
    return __uint_as_float(((unsigned int)h) << 16);
}

// ---------------------------------------------------------------------------
// Kernel 0: weights -> bf16, transposed to fragment-friendly [n][k] layout.
// ---------------------------------------------------------------------------
__global__ __launch_bounds__(256) void prep_weights(
    const float* __restrict__ Wfc1, const float* __restrict__ Wfc2,
    unsigned short* __restrict__ W1T, unsigned short* __restrict__ W2T)
{
    int idx = blockIdx.x * 256 + threadIdx.x;
    if (idx < 4096) {
        int n = idx >> 6, k = idx & 63;
        W1T[idx] = f2b(Wfc1[k * 64 + n]);
    } else if (idx < 18432) {
        int j = idx - 4096;
        int n = j >> 6, k = j & 63;
        W2T[j] = f2b(Wfc2[k * 224 + n]);
    }
}

// ---------------------------------------------------------------------------
// Kernel 1: per-node linear transforms into combined st_vt[n][160].
// ---------------------------------------------------------------------------
__global__ __launch_bounds__(256) void node_prep(
    const float* __restrict__ nf,
    const float* __restrict__ Wnl0,
    const float* __restrict__ Wnl1,
    float* __restrict__ st_vt)
{
    int gid = blockIdx.x * blockDim.x + threadIdx.x;
    if (gid >= N_NODES * 160) return;
    int n = gid / 160;
    int j = gid - n * 160;
    const float* nfn = nf + (size_t)n * 160;

    float acc = 0.f;
    if (j < 64) {
        #pragma unroll 8
        for (int k = 0; k < 64; ++k) acc += nfn[k] * Wnl0[k * 64 + j];
    } else {
        int t = j - 64;
        int k = t / 3, i = t - 3 * k;
        #pragma unroll 8
        for (int m = 0; m < 32; ++m) acc += nfn[64 + m * 3 + i] * Wnl1[m * 32 + k];
    }
    st_vt[(size_t)n * 160 + j] = acc;
}

// ---------------------------------------------------------------------------
// Sorting: histogram of src, exclusive scan, scatter to order[].
// ---------------------------------------------------------------------------
__global__ __launch_bounds__(256) void hist_kernel(
    const int* __restrict__ eidx, int* __restrict__ cnt)
{
    int e = blockIdx.x * 256 + threadIdx.x;
    if (e < N_EDGES) atomicAdd(&cnt[eidx[e]], 1);
}

__global__ __launch_bounds__(1024) void scan_kernel(
    const int* __restrict__ cnt, int* __restrict__ row_start)
{
    __shared__ int part[1024];
    const int t = threadIdx.x;
    const int CH = 10;
    int base = t * CH;
    int s = 0;
    for (int i = 0; i < CH; ++i) {
        int idx = base + i;
        if (idx < N_NODES) s += cnt[idx];
    }
    part[t] = s;
    __syncthreads();
    for (int off = 1; off < 1024; off <<= 1) {
        int v = (t >= off) ? part[t - off] : 0;
        __syncthreads();
        part[t] += v;
        __syncthreads();
    }
    int run = (t == 0) ? 0 : part[t - 1];
    for (int i = 0; i < CH; ++i) {
        int idx = base + i;
        if (idx < N_NODES) { row_start[idx] = run; run += cnt[idx]; }
    }
    if (t == 1023) row_start[N_NODES] = run;
}

__global__ __launch_bounds__(256) void scatter_kernel(
    const int* __restrict__ eidx, const int* __restrict__ row_start,
    int* __restrict__ fill, int* __restrict__ order)
{
    int e = blockIdx.x * 256 + threadIdx.x;
    if (e >= N_EDGES) return;
    int s = eidx[e];
    int p = atomicAdd(&fill[s], 1);
    order[row_start[s] + p] = e;
}

// ---------------------------------------------------------------------------
// Kernel 2: MFMA edge MLP + tensor-product message + segmented scatter.
// 256 threads (4 waves), 32 sorted edges per workgroup.
// GEMM1: H[32,64]=relu(ef@Wfc1), GEMM2: w[32,224]=H@Wfc2, both bf16 MFMA.
// A-tiles in LDS use XOR swizzle (row-stride 128B would be 16-way conflict).
// ---------------------------------------------------------------------------
__global__ __launch_bounds__(256) void edge_conv(
    const float* __restrict__ edge_attr,
    const float* __restrict__ edge_feature,
    const unsigned short* __restrict__ W1T,
    const unsigned short* __restrict__ W2T,
    const int* __restrict__ edge_index,
    const int* __restrict__ order,
    const float* __restrict__ st_vt,
    float* __restrict__ agg)
{
    __shared__ unsigned short A1[32 * 64];    // 4 KB, swizzled
    __shared__ unsigned short Hs[32 * 64];    // 4 KB, swizzled
    __shared__ unsigned short w_s[32 * 224];  // 14 KB
    __shared__ float df_s[32 * 160];          // 20 KB
    __shared__ float sh_s[32][3];
    __shared__ int   eid_s[32];
    __shared__ int   src_s[32];
    __shared__ int   dst_s[32];

    const int tid  = threadIdx.x;
    const int lane = tid & 63;
    const int wv   = tid >> 6;   // wave 0..3
    const int l15  = lane & 15;
    const int g    = lane >> 4;  // 0..3

    // ---- phase 0a: edge ids, src/dst, sh1 ----
    if (tid < 32) {
        int e = order[blockIdx.x * 32 + tid];
        eid_s[tid] = e;
        src_s[tid] = edge_index[e];
        dst_s[tid] = edge_index[N_EDGES + e];
        float x = edge_attr[(size_t)e * 3 + 0];
        float y = edge_attr[(size_t)e * 3 + 1];
        float z = edge_attr[(size_t)e * 3 + 2];
        float inv = SQRT3F / sqrtf(x * x + y * y + z * z);
        sh_s[tid][0] = x * inv;
        sh_s[tid][1] = y * inv;
        sh_s[tid][2] = z * inv;
    }
    __syncthreads();

    // ---- phase 0b: gather ef (bf16, swizzled) + dst node features ----
    #pragma unroll
    for (int r = 0; r < 8; ++r) {
        int idx = tid + r * 256;
        int e = idx >> 6, f = idx & 63;
        float v = edge_feature[(size_t)eid_s[e] * 64 + f];
        A1[e * 64 + (f ^ ((e & 7) << 3))] = f2b(v);
    }
    #pragma unroll
    for (int r = 0; r < 20; ++r) {
        int idx = tid + r * 256;
        int e = idx / 160, f = idx - e * 160;
        df_s[idx] = st_vt[(size_t)dst_s[e] * 160 + f];
    }
    __syncthreads();

    // ---- GEMM1: Hs = relu(A1 @ Wfc1), wave wv owns n-strip nt=wv ----
    {
        const int nt = wv;
        bf16x8 b0 = *reinterpret_cast<const bf16x8*>(&W1T[(nt * 16 + l15) * 64 + g * 8]);
        bf16x8 b1 = *reinterpret_cast<const bf16x8*>(&W1T[(nt * 16 + l15) * 64 + 32 + g * 8]);
        #pragma unroll
        for (int mt = 0; mt < 2; ++mt) {
            f32x4 acc = {0.f, 0.f, 0.f, 0.f};
            int ra = mt * 16 + l15;
            int sw = (ra & 7) << 3;
            bf16x8 a0 = *reinterpret_cast<const bf16x8*>(&A1[ra * 64 + ((g * 8) ^ sw)]);
            bf16x8 a1 = *reinterpret_cast<const bf16x8*>(&A1[ra * 64 + ((32 + g * 8) ^ sw)]);
            acc = __builtin_amdgcn_mfma_f32_16x16x32_bf16(a0, b0, acc, 0, 0, 0);
            acc = __builtin_amdgcn_mfma_f32_16x16x32_bf16(a1, b1, acc, 0, 0, 0);
            #pragma unroll
            for (int r = 0; r < 4; ++r) {
                int row = mt * 16 + g * 4 + r;
                int col = nt * 16 + l15;
                Hs[row * 64 + (col ^ ((row & 7) << 3))] = f2b(fmaxf(acc[r], 0.f));
            }
        }
    }
    __syncthreads();

    // ---- GEMM2: w_s = Hs @ Wfc2; waves own n-strips {4,4,3,3} of 14 ----
    {
        int ntn = (wv < 2) ? 4 : 3;
        int nt0 = wv * 4 - ((wv == 3) ? 1 : 0);
        for (int ii = 0; ii < ntn; ++ii) {
            int nt = nt0 + ii;
            bf16x8 b0 = *reinterpret_cast<const bf16x8*>(&W2T[(nt * 16 + l15) * 64 + g * 8]);
            bf16x8 b1 = *reinterpret_cast<const bf16x8*>(&W2T[(nt * 16 + l15) * 64 + 32 + g * 8]);
            #pragma unroll
            for (int mt = 0; mt < 2; ++mt) {
                f32x4 acc = {0.f, 0.f, 0.f, 0.f};
                int ra = mt * 16 + l15;
                int sw = (ra & 7) << 3;
                bf16x8 a0 = *reinterpret_cast<const bf16x8*>(&Hs[ra * 64 + ((g * 8) ^ sw)]);
                bf16x8 a1 = *reinterpret_cast<const bf16x8*>(&Hs[ra * 64 + ((32 + g * 8) ^ sw)]);
                acc = __builtin_amdgcn_mfma_f32_16x16x32_bf16(a0, b0, acc, 0, 0, 0);
                acc = __builtin_amdgcn_mfma_f32_16x16x32_bf16(a1, b1, acc, 0, 0, 0);
                #pragma unroll
                for (int r = 0; r < 4; ++r) {
                    int row = mt * 16 + g * 4 + r;
                    w_s[row * 224 + nt * 16 + l15] = f2b(acc[r]);
                }
            }
        }
    }
    __syncthreads();

    // ---- phase 3: messages, register-accumulated per src segment ----
    {
        const int idx0 = tid;
        const int idx1 = 256 + tid;
        const bool has1 = (tid < 224);

        auto msg = [&](int idx, int e) -> float {
            const unsigned short* we = &w_s[e * 224];
            const float* df = df_s + e * 160;
            float shx = sh_s[e][0], shy = sh_s[e][1], shz = sh_s[e][2];
            if (idx < 64) {
                return b2f(we[idx]) * df[idx];
            } else if (idx < 96) {
                int k = idx - 64;
                return b2f(we[160 + k]) * (df[64 + 3 * k] * shx + df[65 + 3 * k] * shy +
                                           df[66 + 3 * k] * shz) * INV_SQRT3F;
            } else if (idx < 288) {
                int t = idx - 96;
                int c = t / 3, i = t - 3 * c;
                float sh = (i == 0) ? shx : ((i == 1) ? shy : shz);
                return b2f(we[64 + c]) * df[c] * sh;
            } else if (idx < 384) {
                int t = idx - 288;
                int k = t / 3, i = t - 3 * k;
                return b2f(we[128 + k]) * df[64 + 3 * k + i];
            } else {
                int t = idx - 384;
                int k = t / 3, i = t - 3 * k;
                float a0 = df[64 + 3 * k], a1 = df[65 + 3 * k], a2 = df[66 + 3 * k];
                float c;
                if (i == 0)      c = a1 * shz - a2 * shy;
                else if (i == 1) c = a2 * shx - a0 * shz;
                else             c = a0 * shy - a1 * shx;
                return b2f(we[192 + k]) * c * INV_SQRT2F;
            }
        };

        float a0 = 0.f, a1 = 0.f;
        int cur = src_s[0];
        for (int e = 0; e < 32; ++e) {
            int s = src_s[e];
            if (s != cur) {
                atomicAdd(&agg[(size_t)cur * 480 + idx0], a0);
                if (has1) atomicAdd(&agg[(size_t)cur * 480 + idx1], a1);
                a0 = 0.f; a1 = 0.f; cur = s;
            }
            a0 += msg(idx0, e);
            if (has1) a1 += msg(idx1, e);
        }
        atomicAdd(&agg[(size_t)cur * 480 + idx0], a0);
        if (has1) atomicAdd(&agg[(size_t)cur * 480 + idx1], a1);
    }
}

// ---------------------------------------------------------------------------
// Kernel 3: per-node output transform + gating, skips folded in.
// ---------------------------------------------------------------------------
__global__ __launch_bounds__(128) void out_kernel(
    const float* __restrict__ agg,
    const float* __restrict__ nf,
    const float* __restrict__ Wskip0,
    const float* __restrict__ Wskip1,
    const float* __restrict__ Wout_s,
    const float* __restrict__ Wout_v,
    float* __restrict__ out)
{
    __shared__ float aggl[480];
    __shared__ float os_s[96];
    const int n = blockIdx.x;
    const int tid = threadIdx.x;
    const float* nfn = nf + (size_t)n * 160;

    for (int idx = tid; idx < 480; idx += 128)
        aggl[idx] = agg[(size_t)n * 480 + idx] * (1.f / 32.f);
    __syncthreads();

    if (tid < 96) {
        float acc = 0.f;
        #pragma unroll 8
        for (int k = 0; k < 64; ++k) acc += nfn[k] * Wskip0[k * 96 + tid];
        for (int r = 0; r < 96; ++r) acc += aggl[r] * Wout_s[r * 96 + tid];
        os_s[tid] = acc;
    }
    __syncthreads();

    if (tid < 64) {
        float x = os_s[tid];
        out[(size_t)n * 160 + tid] = x / (1.f + expf(-x));  // silu
    }
    if (tid < 96) {
        int t = tid;
        int k = t / 3, i = t - 3 * k;
        float acc = 0.f;
        #pragma unroll 8
        for (int m = 0; m < 32; ++m) acc += nfn[64 + m * 3 + i] * Wskip1[m * 32 + k];
        #pragma unroll 8
        for (int m = 0; m < 128; ++m) acc += aggl[96 + m * 3 + i] * Wout_v[m * 32 + k];
        float g = os_s[64 + k];
        g = 1.f / (1.f + expf(-g));  // sigmoid gate
        out[(size_t)n * 160 + 64 + t] = g * acc;
    }
}

// ---------------------------------------------------------------------------
extern "C" void kernel_launch(void* const* d_in, const int* in_sizes, int n_in,
                              void* d_out, int out_size, void* d_ws, size_t ws_size,
                              hipStream_t stream)
{
    const float* nf     = (const float*)d_in[0];
    const float* ea     = (const float*)d_in[1];
    const float* ef     = (const float*)d_in[2];
    const float* Wskip0 = (const float*)d_in[3];
    const float* Wskip1 = (const float*)d_in[4];
    const float* Wnl0   = (const float*)d_in[5];
    const float* Wnl1   = (const float*)d_in[6];
    const float* Wfc1   = (const float*)d_in[7];
    const float* Wfc2   = (const float*)d_in[8];
    const float* Wout_s = (const float*)d_in[9];
    const float* Wout_v = (const float*)d_in[10];
    const int*   eidx   = (const int*)d_in[11];
    float* out = (float*)d_out;

    // workspace layout (16B-aligned sections)
    int*   cnt       = (int*)d_ws;                       // 10000
    int*   fill      = cnt + 10000;                      // 10000
    int*   row_start = fill + 10000;                     // 10001 (+pad to 10004)
    int*   order     = row_start + 10004;                // 320000
    float* st_vt     = (float*)(order + 320000);         // 1,600,000
    float* agg       = st_vt + 1600000;                  // 4,800,000
    unsigned short* W1T = (unsigned short*)(agg + 4800000); // 4096
    unsigned short* W2T = W1T + 4096;                       // 14336
    // total ~= 27.1 MB

    hipMemsetAsync(cnt, 0, 20000 * sizeof(int), stream);               // cnt+fill
    hipMemsetAsync(agg, 0, (size_t)N_NODES * 480 * sizeof(float), stream);

    prep_weights<<<72, 256, 0, stream>>>(Wfc1, Wfc2, W1T, W2T);

    node_prep<<<(N_NODES * 160 + 255) / 256, 256, 0, stream>>>(
        nf, Wnl0, Wnl1, st_vt);

    hist_kernel<<<(N_EDGES + 255) / 256, 256, 0, stream>>>(eidx, cnt);
    scan_kernel<<<1, 1024, 0, stream>>>(cnt, row_start);
    scatter_kernel<<<(N_EDGES + 255) / 256, 256, 0, stream>>>(
        eidx, row_start, fill, order);

    edge_conv<<<N_EDGES / 32, 256, 0, stream>>>(
        ea, ef, W1T, W2T, eidx, order, st_vt, agg);

    out_kernel<<<N_NODES, 128, 0, stream>>>(
        agg, nf, Wskip0, Wskip1, Wout_s, Wout_v, out);
}